// Round 1
// baseline (2147.928 us; speedup 1.0000x reference)
//
#include <hip/hip_runtime.h>
#include <hip/hip_bf16.h>
#include <math.h>

typedef __hip_bfloat16 bf16;
typedef short bf16x8 __attribute__((ext_vector_type(8)));
typedef float f32x4 __attribute__((ext_vector_type(4)));

#define BQ 128   // batch
#define TT 20    // timesteps
#define RR 49    // regions
#define DD 2048  // feature dim
#define EE 512   // embed dim
#define HH 512   // hidden
#define VV 10000 // vocab
#define XW 3072  // xcat width = E + D + H
constexpr float EPSV = 1e-5f;
#define APITCH 40  // LDS row pitch in bf16 elems (80B) — breaks pow2 bank stride

__device__ __forceinline__ float sigmoidf(float x) { return 1.f / (1.f + __expf(-x)); }
__device__ __forceinline__ float tanh_fast(float x) {
  float e = __expf(2.f * x);
  return 1.f - 2.f / (e + 1.f);
}
__device__ __forceinline__ bf16 f2b(float v) { return __float2bfloat16(v); }
__device__ __forceinline__ float b2f(bf16 v) { return __bfloat162float(v); }

// ---------------- MFMA GEMM ----------------
// C[M,N] = A[M,K] @ W[N,K]^T + bias, optional relu.
// A,W bf16 K-contiguous. M must be multiple of 128 (grid.y = M/128).
// Split-K: blockIdx.z handles K-range [z*kchunk, (z+1)*kchunk); partial z
// written to Cf + z*pstride; bias added only by chunk 0.
__global__ __launch_bounds__(256) void gemm_mfma(
    const bf16* __restrict__ A, const bf16* __restrict__ W,
    const float* __restrict__ bias,
    float* __restrict__ Cf, bf16* __restrict__ Cb, bf16* __restrict__ Cb2,
    long ldc, long ldc2, int N, int K, int act, int kchunk, long pstride) {
  __shared__ __align__(16) short Alds[128 * APITCH];
  __shared__ __align__(16) short Wlds[64 * APITCH];
  int tid = threadIdx.x;
  int bm = blockIdx.y * 128, bn = blockIdx.x * 64;
  int kz = blockIdx.z;
  int kbeg = kz * kchunk;
  int w = tid >> 6, l = tid & 63;
  int lr = l & 15, lq = l >> 4;              // C col / k-quad
  int srow = tid >> 2, skq = (tid & 3) * 8;  // staging row / k-offset
  const bf16* pa0 = A + (long)(bm + srow) * K + kbeg + skq;
  const bf16* pa1 = pa0 + (long)64 * K;
  const bf16* pw = W + (long)(bn + srow) * K + kbeg + skq;
  bool wok = (bn + srow) < N;
  f32x4 acc[2][4] = {};
  uint4 ra0 = *(const uint4*)pa0;
  uint4 ra1 = *(const uint4*)pa1;
  uint4 rw = wok ? *(const uint4*)pw : make_uint4(0, 0, 0, 0);
  for (int k0 = 0; k0 < kchunk; k0 += 32) {
    __syncthreads();
    *(uint4*)&Alds[srow * APITCH + skq] = ra0;
    *(uint4*)&Alds[(srow + 64) * APITCH + skq] = ra1;
    *(uint4*)&Wlds[srow * APITCH + skq] = rw;
    if (k0 + 32 < kchunk) {  // prefetch next tile (overlaps barrier+MFMA)
      ra0 = *(const uint4*)(pa0 + k0 + 32);
      ra1 = *(const uint4*)(pa1 + k0 + 32);
      rw = wok ? *(const uint4*)(pw + k0 + 32) : make_uint4(0, 0, 0, 0);
    }
    __syncthreads();
    bf16x8 af[2], bfr[4];
#pragma unroll
    for (int mt = 0; mt < 2; ++mt)
      af[mt] = *(const bf16x8*)&Alds[(w * 32 + mt * 16 + lr) * APITCH + lq * 8];
#pragma unroll
    for (int nt = 0; nt < 4; ++nt)
      bfr[nt] = *(const bf16x8*)&Wlds[(nt * 16 + lr) * APITCH + lq * 8];
#pragma unroll
    for (int mt = 0; mt < 2; ++mt)
#pragma unroll
      for (int nt = 0; nt < 4; ++nt)
        acc[mt][nt] = __builtin_amdgcn_mfma_f32_16x16x32_bf16(
            af[mt], bfr[nt], acc[mt][nt], 0, 0, 0);
  }
  if (Cf) Cf += (long)kz * pstride;
  // epilogue: C/D layout col=lane&15, row=(lane>>4)*4+i
#pragma unroll
  for (int mt = 0; mt < 2; ++mt) {
    int gm = bm + w * 32 + mt * 16 + lq * 4;
#pragma unroll
    for (int nt = 0; nt < 4; ++nt) {
      int gn = bn + nt * 16 + lr;
      if (gn >= N) continue;
      float bv = (bias && kz == 0) ? bias[gn] : 0.f;
#pragma unroll
      for (int i = 0; i < 4; ++i) {
        float v = acc[mt][nt][i] + bv;
        if (act) v = fmaxf(v, 0.f);
        long row = gm + i;
        if (Cf) Cf[row * ldc + gn] = v;
        if (Cb) Cb[row * ldc + gn] = f2b(v);
        if (Cb2) Cb2[row * ldc2 + gn] = f2b(v);
      }
    }
  }
}

// ---------------- small kernels ----------------
// mean over R regions -> bf16 [B,D]
__global__ void mean_kernel(const float* __restrict__ feat, bf16* __restrict__ meanbf) {
  int idx = blockIdx.x * blockDim.x + threadIdx.x;
  if (idx >= BQ * DD) return;
  int b = idx / DD, d = idx - b * DD;
  const float* p = feat + (long)b * RR * DD + d;
  float s = 0.f;
  for (int r = 0; r < RR; ++r) s += p[(long)r * DD];
  meanbf[idx] = f2b(s * (1.f / RR));
}

// fp32 -> bf16, 4 elems/thread
__global__ void f2b_kernel(const float* __restrict__ src, bf16* __restrict__ dst, long n4) {
  long i = (long)blockIdx.x * blockDim.x + threadIdx.x;
  if (i >= n4) return;
  float4 v = ((const float4*)src)[i];
  bf16 o[4] = {f2b(v.x), f2b(v.y), f2b(v.z), f2b(v.w)};
  *(ushort4*)(dst + i * 4) = *(const ushort4*)o;
}

// pack [W_ih | W_hh] -> Wcat bf16 [2048][3072]
__global__ void wcat_kernel(const float* __restrict__ W_ih, const float* __restrict__ W_hh,
                            bf16* __restrict__ Wcat) {
  int n = blockIdx.y;
  int kc = (blockIdx.x * blockDim.x + threadIdx.x) * 4;  // 0..3068
  float4 v = (kc < EE + DD) ? *(const float4*)(W_ih + (long)n * (EE + DD) + kc)
                            : *(const float4*)(W_hh + (long)n * HH + (kc - EE - DD));
  bf16 o[4] = {f2b(v.x), f2b(v.y), f2b(v.z), f2b(v.w)};
  *(ushort4*)(Wcat + (long)n * XW + kc) = *(const ushort4*)o;
}

__global__ void biasc_kernel(const float* __restrict__ b_ih, const float* __restrict__ b_hh,
                             float* __restrict__ bc) {
  int i = blockIdx.x * blockDim.x + threadIdx.x;
  if (i < 4 * HH) bc[i] = b_ih[i] + b_hh[i];
}

// Ua [H][H] fp32 -> UaT [k][ch] bf16 (64x64 LDS tile transpose)
__global__ void transpose_ua(const float* __restrict__ Ua, bf16* __restrict__ UaT) {
  __shared__ float tile[64][65];
  int tx = threadIdx.x & 63, ty = threadIdx.x >> 6;
  int c0 = blockIdx.x * 64, k0 = blockIdx.y * 64;
  for (int r = ty; r < 64; r += 4)
    tile[r][tx] = Ua[(long)(c0 + r) * HH + k0 + tx];
  __syncthreads();
  for (int r = ty; r < 64; r += 4)
    UaT[(long)(k0 + r) * HH + c0 + tx] = f2b(tile[tx][r]);
}

// embedding gather for ALL steps -> xcat_all[t][:,0:E] bf16 (hoisted out of loop)
__global__ void embed_all_kernel(const int* __restrict__ cap, const float* __restrict__ emb,
                                 bf16* __restrict__ xcat_all) {
  long idx = (long)blockIdx.x * blockDim.x + threadIdx.x;  // B*T*E/4
  int bt = (int)(idx >> 7);      // E/4 = 128 chunks per (b,t)
  int e4 = ((int)idx & 127) * 4;
  int b = bt / TT, t = bt - b * TT;
  int tok = cap[b * TT + t];
  float4 v = *(const float4*)(emb + (long)tok * EE + e4);
  bf16 o[4] = {f2b(v.x), f2b(v.y), f2b(v.z), f2b(v.w)};
  *(ushort4*)(xcat_all + ((long)t * BQ + b) * XW + e4) = *(const ushort4*)o;
}

// fused: a2 = h@Ua^T+bu; score = va.tanh(att1+a2)+bv; softmax; ctx -> xcat bf16
__global__ __launch_bounds__(256) void attn_fused(
    const bf16* __restrict__ att1, const bf16* __restrict__ hbf,
    const bf16* __restrict__ UaT, const float* __restrict__ bu,
    const float* __restrict__ va, const float* __restrict__ bv,
    const bf16* __restrict__ feat, bf16* __restrict__ xcat,
    float* __restrict__ att_out, int t) {
  int b = blockIdx.x, tid = threadIdx.x;
  __shared__ float hs[HH], a2s[HH], vas[HH];
  __shared__ float sc[64];
  for (int i = tid; i < HH; i += 256) {
    hs[i] = b2f(hbf[b * HH + i]);
    vas[i] = va[i];
  }
  __syncthreads();
  // a2[ch] for ch = 2*tid, 2*tid+1. UaT is [k][ch]: 4B/lane coalesced.
  {
    int ch = tid * 2;
    const bf16* up = UaT + ch;
    float a0 = 0.f, a1 = 0.f, q0 = 0.f, q1 = 0.f;
#pragma unroll 4
    for (int k = 0; k < HH; k += 2) {
      uint u0 = *(const uint*)(up + (long)k * HH);
      uint u1 = *(const uint*)(up + (long)(k + 1) * HH);
      float h0 = hs[k], h1 = hs[k + 1];
      a0 += h0 * b2f(((const bf16*)&u0)[0]);
      a1 += h0 * b2f(((const bf16*)&u0)[1]);
      q0 += h1 * b2f(((const bf16*)&u1)[0]);
      q1 += h1 * b2f(((const bf16*)&u1)[1]);
    }
    a2s[ch] = a0 + q0 + bu[ch];
    a2s[ch + 1] = a1 + q1 + bu[ch + 1];
  }
  __syncthreads();
  int wave = tid >> 6, lane = tid & 63;
  for (int r = wave; r < RR; r += 4) {
    bf16 rv[8];
    *(uint4*)rv = *(const uint4*)(att1 + ((long)b * RR + r) * HH + lane * 8);
    float p = 0.f;
#pragma unroll
    for (int j = 0; j < 8; ++j) {
      int h = lane * 8 + j;
      p += vas[h] * tanh_fast(b2f(rv[j]) + a2s[h]);
    }
#pragma unroll
    for (int off = 32; off > 0; off >>= 1) p += __shfl_down(p, off, 64);
    if (lane == 0) sc[r] = p + bv[0];
  }
  __syncthreads();
  if (tid < 64) {
    float v = (tid < RR) ? sc[tid] : -1e30f;
    float m = v;
#pragma unroll
    for (int off = 32; off > 0; off >>= 1) m = fmaxf(m, __shfl_xor(m, off, 64));
    float e = (tid < RR) ? __expf(v - m) : 0.f;
    float s = e;
#pragma unroll
    for (int off = 32; off > 0; off >>= 1) s += __shfl_xor(s, off, 64);
    float wgt = e / s;
    if (tid < RR) {
      sc[tid] = wgt;
      att_out[((long)b * TT + t) * RR + tid] = wgt;
    }
  }
  __syncthreads();
  // ctx: each thread owns 8 d's
  const bf16* fb = feat + (long)b * RR * DD + tid * 8;
  float accv[8] = {};
  for (int r = 0; r < RR; ++r) {
    bf16 fv[8];
    *(uint4*)fv = *(const uint4*)(fb + (long)r * DD);
    float wr = sc[r];
#pragma unroll
    for (int j = 0; j < 8; ++j) accv[j] += wr * b2f(fv[j]);
  }
  bf16 ov[8];
#pragma unroll
  for (int j = 0; j < 8; ++j) ov[j] = f2b(accv[j]);
  *(uint4*)(xcat + (long)b * XW + EE + tid * 8) = *(const uint4*)ov;
}

// LSTM pointwise + BN1 (biased var, two-pass); sums 4 split-K gate partials;
// writes h (bf16) to hbf and to NEXT step's xcat h-slice
__global__ void lstm_bn_kernel(const float* __restrict__ gates, float* __restrict__ c,
                               bf16* __restrict__ hbf, bf16* __restrict__ xnext,
                               const float* __restrict__ g1, const float* __restrict__ be1) {
  int ch = blockIdx.x;  // 0..511
  int b = threadIdx.x;  // 0..127
  const long GP = (long)BQ * 4 * HH;
  const float* gr = gates + (long)b * 4 * HH;
  float vi = gr[ch] + gr[GP + ch] + gr[2 * GP + ch] + gr[3 * GP + ch];
  float vf = gr[HH + ch] + gr[GP + HH + ch] + gr[2 * GP + HH + ch] + gr[3 * GP + HH + ch];
  float vg = gr[2 * HH + ch] + gr[GP + 2 * HH + ch] + gr[2 * GP + 2 * HH + ch] + gr[3 * GP + 2 * HH + ch];
  float vo = gr[3 * HH + ch] + gr[GP + 3 * HH + ch] + gr[2 * GP + 3 * HH + ch] + gr[3 * GP + 3 * HH + ch];
  float ig = sigmoidf(vi);
  float fg = sigmoidf(vf);
  float gg = tanh_fast(vg);
  float og = sigmoidf(vo);
  float cn = fg * c[b * HH + ch] + ig * gg;
  c[b * HH + ch] = cn;
  float hr = og * tanh_fast(cn);
  __shared__ float s1[128];
  s1[b] = hr;
  __syncthreads();
  for (int off = 64; off > 0; off >>= 1) {
    if (b < off) s1[b] += s1[b + off];
    __syncthreads();
  }
  float mean = s1[0] * (1.f / 128);
  __syncthreads();
  float dv = hr - mean;
  s1[b] = dv * dv;
  __syncthreads();
  for (int off = 64; off > 0; off >>= 1) {
    if (b < off) s1[b] += s1[b + off];
    __syncthreads();
  }
  float var = s1[0] * (1.f / 128);
  float res = dv * (1.f / sqrtf(var + EPSV)) * g1[ch] + be1[ch];
  hbf[b * HH + ch] = f2b(res);
  xnext[(long)b * XW + EE + DD + ch] = f2b(res);
}

// fused fc (relu) + BN2: block owns 8 whole channel-columns so BN batch
// stats are block-local. grid 32 x 256 threads; thread = (b, 4 channels).
__global__ __launch_bounds__(256) void fc_bn2_kernel(
    const bf16* __restrict__ hbf, const bf16* __restrict__ fcw,
    const float* __restrict__ fcb, const float* __restrict__ g2,
    const float* __restrict__ be2, bf16* __restrict__ out2) {
  int tid = threadIdx.x;
  int ch0 = blockIdx.x * 8;
  __shared__ __align__(16) short wlds[8 * 512];  // 8 fc_w rows, bf16
  __shared__ float red[8][130];
  __shared__ float stat[8];
  for (int i = tid; i < 8 * 512 / 8; i += 256)
    *(bf16x8*)&wlds[i * 8] = *(const bf16x8*)(fcw + (long)ch0 * HH + i * 8);
  __syncthreads();
  int b = tid & 127, cg = tid >> 7;  // cg in {0,1}: channels cg*4..cg*4+3
  const bf16* hr = hbf + (long)b * HH;
  float acc[4] = {};
  for (int k = 0; k < HH; k += 8) {
    bf16 hv[8];
    *(uint4*)hv = *(const uint4*)(hr + k);
    float hf[8];
#pragma unroll
    for (int j = 0; j < 8; ++j) hf[j] = b2f(hv[j]);
#pragma unroll
    for (int jc = 0; jc < 4; ++jc) {
      const bf16* wr = (const bf16*)&wlds[(cg * 4 + jc) * 512 + k];
#pragma unroll
      for (int j = 0; j < 8; ++j) acc[jc] += hf[j] * b2f(wr[j]);
    }
  }
  float val[4], dv[4];
#pragma unroll
  for (int jc = 0; jc < 4; ++jc) {
    int cl = cg * 4 + jc;
    val[jc] = fmaxf(acc[jc] + fcb[ch0 + cl], 0.f);
    red[cl][b] = val[jc];
  }
  __syncthreads();
  if (tid < 8) {
    float s = 0.f;
    for (int i = 0; i < 128; i += 4)
      s += red[tid][i] + red[tid][i + 1] + red[tid][i + 2] + red[tid][i + 3];
    stat[tid] = s * (1.f / 128);
  }
  __syncthreads();
#pragma unroll
  for (int jc = 0; jc < 4; ++jc) {
    int cl = cg * 4 + jc;
    dv[jc] = val[jc] - stat[cl];
    red[cl][b] = dv[jc] * dv[jc];
  }
  __syncthreads();
  if (tid < 8) {
    float s = 0.f;
    for (int i = 0; i < 128; i += 4)
      s += red[tid][i] + red[tid][i + 1] + red[tid][i + 2] + red[tid][i + 3];
    float var = s * (1.f / 128);
    stat[tid] = 1.f / sqrtf(var + EPSV);
  }
  __syncthreads();
#pragma unroll
  for (int jc = 0; jc < 4; ++jc) {
    int cl = cg * 4 + jc;
    out2[(long)b * 256 + ch0 + cl] = f2b(dv[jc] * stat[cl] * g2[ch0 + cl] + be2[ch0 + cl]);
  }
}

extern "C" void kernel_launch(void* const* d_in, const int* in_sizes, int n_in,
                              void* d_out, int out_size, void* d_ws, size_t ws_size,
                              hipStream_t stream) {
  const int* captions  = (const int*)d_in[0];
  const float* features = (const float*)d_in[1];
  const float* emb   = (const float*)d_in[2];
  const float* Wa    = (const float*)d_in[3];
  const float* ba    = (const float*)d_in[4];
  const float* Ua    = (const float*)d_in[5];
  const float* bu    = (const float*)d_in[6];
  const float* va    = (const float*)d_in[7];
  const float* bv    = (const float*)d_in[8];
  const float* W_ih  = (const float*)d_in[9];
  const float* b_ih  = (const float*)d_in[10];
  const float* W_hh  = (const float*)d_in[11];
  const float* b_hh  = (const float*)d_in[12];
  const float* g1    = (const float*)d_in[13];
  const float* be1   = (const float*)d_in[14];
  const float* fc_w  = (const float*)d_in[15];
  const float* fc_b  = (const float*)d_in[16];
  const float* g2    = (const float*)d_in[17];
  const float* be2   = (const float*)d_in[18];
  const float* fc2_w = (const float*)d_in[19];
  const float* fc2_b = (const float*)d_in[20];
  const float* ih_w  = (const float*)d_in[21];
  const float* ih_b  = (const float*)d_in[22];
  const float* ic_w  = (const float*)d_in[23];
  const float* ic_b  = (const float*)d_in[24];

  float* out = (float*)d_out;                 // [B,T,V]
  float* att_out = out + (long)BQ * TT * VV;  // [B,T,R]

  char* p = (char*)d_ws;
  auto alloc = [&](size_t bytes) { char* r = p; p += (bytes + 255) & ~255ULL; return r; };
  bf16* featbf = (bf16*)alloc((size_t)BQ * RR * DD * 2);
  bf16* meanbf = (bf16*)alloc((size_t)BQ * DD * 2);
  bf16* Wcat   = (bf16*)alloc((size_t)4 * HH * XW * 2);
  bf16* Wabf   = (bf16*)alloc((size_t)HH * DD * 2);
  bf16* UaTbf  = (bf16*)alloc((size_t)HH * HH * 2);
  bf16* fcwbf  = (bf16*)alloc((size_t)256 * HH * 2);
  bf16* fc2wbf = (bf16*)alloc((size_t)VV * 256 * 2);
  bf16* ihwbf  = (bf16*)alloc((size_t)HH * DD * 2);
  bf16* icwbf  = (bf16*)alloc((size_t)HH * DD * 2);
  bf16* att1bf = (bf16*)alloc((size_t)BQ * RR * HH * 2);
  bf16* xcat_all = (bf16*)alloc((size_t)(TT + 1) * BQ * XW * 2);  // per-step xcat
  bf16* hbf    = (bf16*)alloc((size_t)BQ * HH * 2);
  bf16* out2bf = (bf16*)alloc((size_t)BQ * 256 * 2);
  float* biasc = (float*)alloc((size_t)4 * HH * 4);
  float* c     = (float*)alloc((size_t)BQ * HH * 4);
  float* gates = (float*)alloc((size_t)4 * BQ * 4 * HH * 4);  // 4 split-K partials

  // ---- prologue: dtype conversion / packing ----
  f2b_kernel<<<(BQ * RR * DD / 4 + 255) / 256, 256, 0, stream>>>(features, featbf, BQ * RR * DD / 4);
  f2b_kernel<<<(HH * DD / 4 + 255) / 256, 256, 0, stream>>>(Wa, Wabf, HH * DD / 4);
  transpose_ua<<<dim3(8, 8), 256, 0, stream>>>(Ua, UaTbf);
  f2b_kernel<<<(256 * HH / 4 + 255) / 256, 256, 0, stream>>>(fc_w, fcwbf, 256 * HH / 4);
  f2b_kernel<<<(VV * 256 / 4 + 255) / 256, 256, 0, stream>>>(fc2_w, fc2wbf, VV * 256 / 4);
  f2b_kernel<<<(HH * DD / 4 + 255) / 256, 256, 0, stream>>>(ih_w, ihwbf, HH * DD / 4);
  f2b_kernel<<<(HH * DD / 4 + 255) / 256, 256, 0, stream>>>(ic_w, icwbf, HH * DD / 4);
  wcat_kernel<<<dim3(XW / 4 / 256, 4 * HH), 256, 0, stream>>>(W_ih, W_hh, Wcat);
  biasc_kernel<<<(4 * HH + 255) / 256, 256, 0, stream>>>(b_ih, b_hh, biasc);
  mean_kernel<<<(BQ * DD + 255) / 256, 256, 0, stream>>>(features, meanbf);
  embed_all_kernel<<<(BQ * TT * EE / 4) / 256, 256, 0, stream>>>(captions, emb, xcat_all);

  // h0 -> hbf + xcat_0 h-slice; c0 -> c (fp32)
  gemm_mfma<<<dim3(HH / 64, 1), 256, 0, stream>>>(
      meanbf, ihwbf, ih_b, nullptr, hbf, xcat_all + EE + DD, HH, XW, HH, DD, 0, DD, 0);
  gemm_mfma<<<dim3(HH / 64, 1), 256, 0, stream>>>(
      meanbf, icwbf, ic_b, c, nullptr, nullptr, HH, 0, HH, DD, 0, DD, 0);
  // att1 = features @ Wa^T + ba  (bf16 out)
  gemm_mfma<<<dim3(HH / 64, BQ * RR / 128), 256, 0, stream>>>(
      featbf, Wabf, ba, nullptr, att1bf, nullptr, HH, 0, HH, DD, 0, DD, 0);

  // ---- timestep loop: 5 kernels/step ----
  for (int t = 0; t < TT; ++t) {
    bf16* xc = xcat_all + (size_t)t * BQ * XW;
    bf16* xn = xcat_all + (size_t)(t + 1) * BQ * XW;
    attn_fused<<<BQ, 256, 0, stream>>>(att1bf, hbf, UaTbf, bu, va, bv, featbf, xc, att_out, t);
    gemm_mfma<<<dim3(4 * HH / 64, 1, 4), 256, 0, stream>>>(
        xc, Wcat, biasc, gates, nullptr, nullptr, 4 * HH, 0, 4 * HH, XW, 0,
        XW / 4, (long)BQ * 4 * HH);
    lstm_bn_kernel<<<HH, 128, 0, stream>>>(gates, c, hbf, xn, g1, be1);
    fc_bn2_kernel<<<32, 256, 0, stream>>>(hbf, fcwbf, fc_b, g2, be2, out2bf);
    gemm_mfma<<<dim3((VV + 63) / 64, 1), 256, 0, stream>>>(
        out2bf, fc2wbf, fc2_b, out + (long)t * VV, nullptr, nullptr,
        (long)TT * VV, 0, VV, 256, 0, 256, 0);
  }
}

// Round 3
// 1474.186 us; speedup vs baseline: 1.4570x; 1.4570x over previous
//
#include <hip/hip_runtime.h>
#include <hip/hip_bf16.h>
#include <math.h>

typedef __hip_bfloat16 bf16;
typedef short bf16x8 __attribute__((ext_vector_type(8)));
typedef float f32x4 __attribute__((ext_vector_type(4)));

#define BQ 128   // batch
#define TT 20    // timesteps
#define RR 49    // regions
#define DD 2048  // feature dim
#define EE 512   // embed dim
#define HH 512   // hidden
#define VV 10000 // vocab
#define XW 3072  // xcat width = E + D + H
constexpr float EPSV = 1e-5f;
#define APITCH 40  // LDS row pitch in bf16 elems (80B) — breaks pow2 bank stride

__device__ __forceinline__ float sigmoidf(float x) { return 1.f / (1.f + __expf(-x)); }
__device__ __forceinline__ float tanh_fast(float x) {
  float e = __expf(2.f * x);
  return 1.f - 2.f / (e + 1.f);
}
__device__ __forceinline__ bf16 f2b(float v) { return __float2bfloat16(v); }
__device__ __forceinline__ float b2f(bf16 v) { return __bfloat162float(v); }

// ---------------- MFMA GEMM (prologue only) ----------------
// C[M,N] = A[M,K] @ W[N,K]^T + bias. A,W bf16 K-contiguous.
// transC: store Cf[gn*ldc + row] instead of Cf[row*ldc + gn].
__global__ __launch_bounds__(256) void gemm_mfma(
    const bf16* __restrict__ A, const bf16* __restrict__ W,
    const float* __restrict__ bias,
    float* __restrict__ Cf, bf16* __restrict__ Cb, bf16* __restrict__ Cb2,
    long ldc, long ldc2, int N, int K, int act, int transC) {
  __shared__ __align__(16) short Alds[128 * APITCH];
  __shared__ __align__(16) short Wlds[64 * APITCH];
  int tid = threadIdx.x;
  int bm = blockIdx.y * 128, bn = blockIdx.x * 64;
  int w = tid >> 6, l = tid & 63;
  int lr = l & 15, lq = l >> 4;              // C col / k-quad
  int srow = tid >> 2, skq = (tid & 3) * 8;  // staging row / k-offset
  const bf16* pa0 = A + (long)(bm + srow) * K + skq;
  const bf16* pa1 = pa0 + (long)64 * K;
  const bf16* pw = W + (long)(bn + srow) * K + skq;
  bool wok = (bn + srow) < N;
  f32x4 acc[2][4] = {};
  uint4 ra0 = *(const uint4*)pa0;
  uint4 ra1 = *(const uint4*)pa1;
  uint4 rw = wok ? *(const uint4*)pw : make_uint4(0, 0, 0, 0);
  for (int k0 = 0; k0 < K; k0 += 32) {
    __syncthreads();
    *(uint4*)&Alds[srow * APITCH + skq] = ra0;
    *(uint4*)&Alds[(srow + 64) * APITCH + skq] = ra1;
    *(uint4*)&Wlds[srow * APITCH + skq] = rw;
    if (k0 + 32 < K) {
      ra0 = *(const uint4*)(pa0 + k0 + 32);
      ra1 = *(const uint4*)(pa1 + k0 + 32);
      rw = wok ? *(const uint4*)(pw + k0 + 32) : make_uint4(0, 0, 0, 0);
    }
    __syncthreads();
    bf16x8 af[2], bfr[4];
#pragma unroll
    for (int mt = 0; mt < 2; ++mt)
      af[mt] = *(const bf16x8*)&Alds[(w * 32 + mt * 16 + lr) * APITCH + lq * 8];
#pragma unroll
    for (int nt = 0; nt < 4; ++nt)
      bfr[nt] = *(const bf16x8*)&Wlds[(nt * 16 + lr) * APITCH + lq * 8];
#pragma unroll
    for (int mt = 0; mt < 2; ++mt)
#pragma unroll
      for (int nt = 0; nt < 4; ++nt)
        acc[mt][nt] = __builtin_amdgcn_mfma_f32_16x16x32_bf16(
            af[mt], bfr[nt], acc[mt][nt], 0, 0, 0);
  }
#pragma unroll
  for (int mt = 0; mt < 2; ++mt) {
    int gm = bm + w * 32 + mt * 16 + lq * 4;
#pragma unroll
    for (int nt = 0; nt < 4; ++nt) {
      int gn = bn + nt * 16 + lr;
      if (gn >= N) continue;
      float bv = bias ? bias[gn] : 0.f;
#pragma unroll
      for (int i = 0; i < 4; ++i) {
        float v = acc[mt][nt][i] + bv;
        if (act) v = fmaxf(v, 0.f);
        long row = gm + i;
        if (Cf) {
          if (transC) Cf[(long)gn * ldc + row] = v;
          else Cf[row * ldc + gn] = v;
        }
        if (Cb) Cb[row * ldc + gn] = f2b(v);
        if (Cb2) Cb2[row * ldc2 + gn] = f2b(v);
      }
    }
  }
}

// ---------------- small kernels ----------------
// mean over R regions (bf16 in) -> bf16 [B,D]
__global__ void mean_kernel(const bf16* __restrict__ feat, bf16* __restrict__ meanbf) {
  int idx = blockIdx.x * blockDim.x + threadIdx.x;
  if (idx >= BQ * DD) return;
  int b = idx / DD, d = idx - b * DD;
  const bf16* p = feat + (long)b * RR * DD + d;
  float s = 0.f;
  for (int r = 0; r < RR; ++r) s += b2f(p[(long)r * DD]);
  meanbf[idx] = f2b(s * (1.f / RR));
}

// fp32 -> bf16, 4 elems/thread
__global__ void f2b_kernel(const float* __restrict__ src, bf16* __restrict__ dst, long n4) {
  long i = (long)blockIdx.x * blockDim.x + threadIdx.x;
  if (i >= n4) return;
  float4 v = ((const float4*)src)[i];
  bf16 o[4] = {f2b(v.x), f2b(v.y), f2b(v.z), f2b(v.w)};
  *(ushort4*)(dst + i * 4) = *(const ushort4*)o;
}

// pack [W_ih | W_hh] -> Wcat bf16 [2048][3072]
__global__ void wcat_kernel(const float* __restrict__ W_ih, const float* __restrict__ W_hh,
                            bf16* __restrict__ Wcat) {
  int n = blockIdx.y;
  int kc = (blockIdx.x * blockDim.x + threadIdx.x) * 4;
  float4 v = (kc < EE + DD) ? *(const float4*)(W_ih + (long)n * (EE + DD) + kc)
                            : *(const float4*)(W_hh + (long)n * HH + (kc - EE - DD));
  bf16 o[4] = {f2b(v.x), f2b(v.y), f2b(v.z), f2b(v.w)};
  *(ushort4*)(Wcat + (long)n * XW + kc) = *(const ushort4*)o;
}

__global__ void biasc_kernel(const float* __restrict__ b_ih, const float* __restrict__ b_hh,
                             float* __restrict__ bc) {
  int i = blockIdx.x * blockDim.x + threadIdx.x;
  if (i < 4 * HH) bc[i] = b_ih[i] + b_hh[i];
}

// Ua [H][H] fp32 -> UaT [k][ch] bf16 (64x64 LDS tile transpose)
__global__ void transpose_ua(const float* __restrict__ Ua, bf16* __restrict__ UaT) {
  __shared__ float tile[64][65];
  int tx = threadIdx.x & 63, ty = threadIdx.x >> 6;
  int c0 = blockIdx.x * 64, k0 = blockIdx.y * 64;
  for (int r = ty; r < 64; r += 4)
    tile[r][tx] = Ua[(long)(c0 + r) * HH + k0 + tx];
  __syncthreads();
  for (int r = ty; r < 64; r += 4)
    UaT[(long)(k0 + r) * HH + c0 + tx] = f2b(tile[tx][r]);
}

// embedding gather for ALL steps -> xcat_all[t][:,0:E] bf16
__global__ void embed_all_kernel(const int* __restrict__ cap, const float* __restrict__ emb,
                                 bf16* __restrict__ xcat_all) {
  long idx = (long)blockIdx.x * blockDim.x + threadIdx.x;
  int bt = (int)(idx >> 7);
  int e4 = ((int)idx & 127) * 4;
  int b = bt / TT, t = bt - b * TT;
  int tok = cap[b * TT + t];
  float4 v = *(const float4*)(emb + (long)tok * EE + e4);
  bf16 o[4] = {f2b(v.x), f2b(v.y), f2b(v.z), f2b(v.w)};
  *(ushort4*)(xcat_all + ((long)t * BQ + b) * XW + e4) = *(const ushort4*)o;
}

// ================= K2: attn(t) [blocks 0..127] || fc1+BN2(t-1) [blocks 128..159]
__global__ __launch_bounds__(512) void step_attn_fc(
    const bf16* __restrict__ att1, const bf16* __restrict__ hbf,
    const bf16* __restrict__ UaT, const float* __restrict__ bu,
    const float* __restrict__ va, const float* __restrict__ bv,
    const bf16* __restrict__ feat, bf16* __restrict__ xcat,
    float* __restrict__ att_out, int t, int do_attn,
    const bf16* __restrict__ fcw, const float* __restrict__ fcb,
    const float* __restrict__ g2, const float* __restrict__ be2,
    bf16* __restrict__ out2, int do_fc) {
  __shared__ __align__(16) char smem[29824];
  int blk = blockIdx.x, tid = threadIdx.x;
  if (blk < 128) {
    // ---------- attention segment ----------
    if (!do_attn) return;
    int b = blk;
    float* hs = (float*)smem;        // 512
    float* vas = hs + 512;           // 512
    float* a2s = vas + 512;          // 512
    float* a2p = a2s + 512;          // 1024
    float* sc = a2p + 1024;          // 64
    hs[tid] = b2f(hbf[b * HH + tid]);
    vas[tid] = va[tid];
    __syncthreads();
    // a2 = h @ Ua^T + bu, split over k-halves: tid<256 -> k[0,256), else k[256,512)
    {
      int half = tid >> 8, cp = (tid & 255) * 2;
      const bf16* up = UaT + (long)(half * 256) * HH + cp;
      const float* hh = hs + half * 256;
      float a0 = 0.f, a1 = 0.f;
#pragma unroll 8
      for (int k = 0; k < 256; ++k) {
        uint u = *(const uint*)(up + (long)k * HH);
        float hk = hh[k];
        a0 += hk * b2f(((const bf16*)&u)[0]);
        a1 += hk * b2f(((const bf16*)&u)[1]);
      }
      a2p[half * 512 + cp] = a0;
      a2p[half * 512 + cp + 1] = a1;
    }
    __syncthreads();
    if (tid < 256) {
      int ch = tid * 2;
      a2s[ch] = a2p[ch] + a2p[512 + ch] + bu[ch];
      a2s[ch + 1] = a2p[ch + 1] + a2p[512 + ch + 1] + bu[ch + 1];
    }
    __syncthreads();
    int wave = tid >> 6, lane = tid & 63;
    // hoist per-lane va / a2 slices to registers (reused across score rows)
    float vreg[8], areg[8];
    *(float4*)&vreg[0] = *(const float4*)&vas[lane * 8];
    *(float4*)&vreg[4] = *(const float4*)&vas[lane * 8 + 4];
    *(float4*)&areg[0] = *(const float4*)&a2s[lane * 8];
    *(float4*)&areg[4] = *(const float4*)&a2s[lane * 8 + 4];
    for (int r = wave; r < RR; r += 8) {
      bf16 rv[8];
      *(uint4*)rv = *(const uint4*)(att1 + ((long)b * RR + r) * HH + lane * 8);
      float p = 0.f;
#pragma unroll
      for (int j = 0; j < 8; ++j)
        p += vreg[j] * tanh_fast(b2f(rv[j]) + areg[j]);
#pragma unroll
      for (int off = 32; off > 0; off >>= 1) p += __shfl_down(p, off, 64);
      if (lane == 0) sc[r] = p + bv[0];
    }
    __syncthreads();
    if (tid < 64) {
      float v = (tid < RR) ? sc[tid] : -1e30f;
      float m = v;
#pragma unroll
      for (int off = 32; off > 0; off >>= 1) m = fmaxf(m, __shfl_xor(m, off, 64));
      float e = (tid < RR) ? __expf(v - m) : 0.f;
      float s = e;
#pragma unroll
      for (int off = 32; off > 0; off >>= 1) s += __shfl_xor(s, off, 64);
      float wgt = e / s;
      if (tid < RR) {
        sc[tid] = wgt;
        att_out[((long)b * TT + t) * RR + tid] = wgt;
      }
    }
    __syncthreads();
    // ctx: 512 threads x 4 d's
    const bf16* fb = feat + (long)b * RR * DD + tid * 4;
    float ac[4] = {};
    for (int r = 0; r < RR; ++r) {
      uint2 u = *(const uint2*)(fb + (long)r * DD);
      const bf16* pv = (const bf16*)&u;
      float wr = sc[r];
#pragma unroll
      for (int j = 0; j < 4; ++j) ac[j] += wr * b2f(pv[j]);
    }
    bf16 ov[4];
#pragma unroll
    for (int j = 0; j < 4; ++j) ov[j] = f2b(ac[j]);
    *(uint2*)(xcat + (long)b * XW + EE + tid * 4) = *(const uint2*)ov;
  } else {
    // ---------- fc1 + ReLU + BN2 segment ----------
    if (!do_fc) return;
    int ch0 = (blk - 128) * 8;
    short* wlds = (short*)smem;              // 8*512 = 4096 shorts
    short* hlds = wlds + 4096;               // 128 rows x 68 pitch = 8704 shorts
    float* red = (float*)(smem + (4096 + 8704) * 2);  // [8][130]
    float* stat = red + 8 * 130;
    const int HP = 68;  // 136B pitch -> only 2-way bank alias
    *(bf16x8*)&wlds[tid * 8] = *(const bf16x8*)(fcw + (long)ch0 * HH + tid * 8);
    int b = tid & 127, cg = tid >> 7;  // cg in 0..3, 2 channels each
    float acc2[2] = {0.f, 0.f};
    // staging: 512 threads cover 64 rows x 64 cols per uint4; each thread
    // writes rows srow and srow+64 -> all 128 rows of cols [k0,k0+64)
    int srow = tid >> 3, sc8 = (tid & 7) * 8;
    for (int k0 = 0; k0 < HH; k0 += 64) {
      __syncthreads();
      *(uint4*)&hlds[srow * HP + sc8] =
          *(const uint4*)(hbf + (long)srow * HH + k0 + sc8);
      *(uint4*)&hlds[(srow + 64) * HP + sc8] =
          *(const uint4*)(hbf + (long)(srow + 64) * HH + k0 + sc8);
      __syncthreads();
#pragma unroll
      for (int kk = 0; kk < 64; kk += 8) {
        bf16 hv[8];
        *(uint4*)hv = *(const uint4*)&hlds[b * HP + kk];
        float hf[8];
#pragma unroll
        for (int j = 0; j < 8; ++j) hf[j] = b2f(hv[j]);
#pragma unroll
        for (int jc = 0; jc < 2; ++jc) {
          const bf16* wr = (const bf16*)&wlds[(cg * 2 + jc) * 512 + k0 + kk];
#pragma unroll
          for (int j = 0; j < 8; ++j) acc2[jc] += hf[j] * b2f(wr[j]);
        }
      }
    }
    float val2[2], dv2[2];
#pragma unroll
    for (int jc = 0; jc < 2; ++jc) {
      int cl = cg * 2 + jc;
      val2[jc] = fmaxf(acc2[jc] + fcb[ch0 + cl], 0.f);
      red[cl * 130 + b] = val2[jc];
    }
    __syncthreads();
    if (tid < 8) {
      float s = 0.f;
      for (int i = 0; i < 128; i += 4)
        s += red[tid * 130 + i] + red[tid * 130 + i + 1] +
             red[tid * 130 + i + 2] + red[tid * 130 + i + 3];
      stat[tid] = s * (1.f / 128);
    }
    __syncthreads();
#pragma unroll
    for (int jc = 0; jc < 2; ++jc) {
      int cl = cg * 2 + jc;
      dv2[jc] = val2[jc] - stat[cl];
      red[cl * 130 + b] = dv2[jc] * dv2[jc];
    }
    __syncthreads();
    if (tid < 8) {
      float s = 0.f;
      for (int i = 0; i < 128; i += 4)
        s += red[tid * 130 + i] + red[tid * 130 + i + 1] +
             red[tid * 130 + i + 2] + red[tid * 130 + i + 3];
      stat[tid] = 1.f / sqrtf(s * (1.f / 128) + EPSV);
    }
    __syncthreads();
#pragma unroll
    for (int jc = 0; jc < 2; ++jc) {
      int cl = cg * 2 + jc;
      out2[(long)b * 256 + ch0 + cl] =
          f2b(dv2[jc] * stat[cl] * g2[ch0 + cl] + be2[ch0 + cl]);
    }
  }
}

// ================= K3: gates GEMM split-K x4 [blocks 0..127] || fc2 [128..284]
__global__ __launch_bounds__(256) void step_gemms(
    const bf16* __restrict__ xc, const bf16* __restrict__ Wcat,
    const float* __restrict__ biasc, float* __restrict__ gatesT,
    const bf16* __restrict__ out2, const bf16* __restrict__ fc2w,
    const float* __restrict__ fc2b, float* __restrict__ outp,
    int do_gates, int do_fc2) {
  __shared__ __align__(16) short Alds[128 * APITCH];
  __shared__ __align__(16) short Wlds[64 * APITCH];
  int blk = blockIdx.x, tid = threadIdx.x;
  int w = tid >> 6, l = tid & 63;
  int lr = l & 15, lq = l >> 4;
  int srow = tid >> 2, skq = (tid & 3) * 8;
  if (blk < 128) {
    if (!do_gates) return;
    const int KC = XW / 4;  // 768
    int bn = (blk & 31) * 64, kz = blk >> 5, kbeg = kz * KC;
    const bf16* pa0 = xc + (long)srow * XW + kbeg + skq;
    const bf16* pa1 = pa0 + (long)64 * XW;
    const bf16* pw = Wcat + (long)(bn + srow) * XW + kbeg + skq;
    f32x4 acc[2][4] = {};
    uint4 ra0 = *(const uint4*)pa0;
    uint4 ra1 = *(const uint4*)pa1;
    uint4 rw = *(const uint4*)pw;
    for (int k0 = 0; k0 < KC; k0 += 32) {
      __syncthreads();
      *(uint4*)&Alds[srow * APITCH + skq] = ra0;
      *(uint4*)&Alds[(srow + 64) * APITCH + skq] = ra1;
      *(uint4*)&Wlds[srow * APITCH + skq] = rw;
      if (k0 + 32 < KC) {
        ra0 = *(const uint4*)(pa0 + k0 + 32);
        ra1 = *(const uint4*)(pa1 + k0 + 32);
        rw = *(const uint4*)(pw + k0 + 32);
      }
      __syncthreads();
      bf16x8 af[2], bfr[4];
#pragma unroll
      for (int mt = 0; mt < 2; ++mt)
        af[mt] = *(const bf16x8*)&Alds[(w * 32 + mt * 16 + lr) * APITCH + lq * 8];
#pragma unroll
      for (int nt = 0; nt < 4; ++nt)
        bfr[nt] = *(const bf16x8*)&Wlds[(nt * 16 + lr) * APITCH + lq * 8];
#pragma unroll
      for (int mt = 0; mt < 2; ++mt)
#pragma unroll
        for (int nt = 0; nt < 4; ++nt)
          acc[mt][nt] = __builtin_amdgcn_mfma_f32_16x16x32_bf16(
              af[mt], bfr[nt], acc[mt][nt], 0, 0, 0);
    }
    // transposed epilogue: gatesT[kz][gn][b]
    float* Cf = gatesT + (long)kz * 4 * HH * 128;
#pragma unroll
    for (int mt = 0; mt < 2; ++mt) {
      int gm = w * 32 + mt * 16 + lq * 4;
#pragma unroll
      for (int nt = 0; nt < 4; ++nt) {
        int gn = bn + nt * 16 + lr;
        float bv = (kz == 0) ? biasc[gn] : 0.f;
#pragma unroll
        for (int i = 0; i < 4; ++i)
          Cf[(long)gn * 128 + gm + i] = acc[mt][nt][i] + bv;
      }
    }
  } else {
    if (!do_fc2) return;
    int bn = (blk - 128) * 64;
    const bf16* pa0 = out2 + (long)srow * 256 + skq;
    const bf16* pa1 = pa0 + (long)64 * 256;
    const bf16* pw = fc2w + (long)(bn + srow) * 256 + skq;
    bool wok = (bn + srow) < VV;
    f32x4 acc[2][4] = {};
    uint4 ra0 = *(const uint4*)pa0;
    uint4 ra1 = *(const uint4*)pa1;
    uint4 rw = wok ? *(const uint4*)pw : make_uint4(0, 0, 0, 0);
    for (int k0 = 0; k0 < 256; k0 += 32) {
      __syncthreads();
      *(uint4*)&Alds[srow * APITCH + skq] = ra0;
      *(uint4*)&Alds[(srow + 64) * APITCH + skq] = ra1;
      *(uint4*)&Wlds[srow * APITCH + skq] = rw;
      if (k0 + 32 < 256) {
        ra0 = *(const uint4*)(pa0 + k0 + 32);
        ra1 = *(const uint4*)(pa1 + k0 + 32);
        rw = wok ? *(const uint4*)(pw + k0 + 32) : make_uint4(0, 0, 0, 0);
      }
      __syncthreads();
      bf16x8 af[2], bfr[4];
#pragma unroll
      for (int mt = 0; mt < 2; ++mt)
        af[mt] = *(const bf16x8*)&Alds[(w * 32 + mt * 16 + lr) * APITCH + lq * 8];
#pragma unroll
      for (int nt = 0; nt < 4; ++nt)
        bfr[nt] = *(const bf16x8*)&Wlds[(nt * 16 + lr) * APITCH + lq * 8];
#pragma unroll
      for (int mt = 0; mt < 2; ++mt)
#pragma unroll
        for (int nt = 0; nt < 4; ++nt)
          acc[mt][nt] = __builtin_amdgcn_mfma_f32_16x16x32_bf16(
              af[mt], bfr[nt], acc[mt][nt], 0, 0, 0);
    }
    const long ldc = (long)TT * VV;
#pragma unroll
    for (int mt = 0; mt < 2; ++mt) {
      int gm = w * 32 + mt * 16 + lq * 4;
#pragma unroll
      for (int nt = 0; nt < 4; ++nt) {
        int gn = bn + nt * 16 + lr;
        if (gn >= VV) continue;
        float bv = fc2b[gn];
#pragma unroll
        for (int i = 0; i < 4; ++i)
          outp[(long)(gm + i) * ldc + gn] = acc[mt][nt][i] + bv;
      }
    }
  }
}

// ================= K1: LSTM pointwise + BN1 (transposed gates, coalesced)
__global__ __launch_bounds__(256) void lstm_bn2(
    const float* __restrict__ gatesT, float* __restrict__ cT,
    bf16* __restrict__ hbf, bf16* __restrict__ xnext,
    const float* __restrict__ g1, const float* __restrict__ be1) {
  int tid = threadIdx.x;
  int b = tid & 127, sub = tid >> 7;
  int ch = blockIdx.x * 2 + sub;
  const long GP = (long)4 * HH * 128;
  float vi = 0.f, vf = 0.f, vg = 0.f, vo = 0.f;
#pragma unroll
  for (int z = 0; z < 4; ++z) {
    const float* gz = gatesT + z * GP + (long)ch * 128 + b;
    vi += gz[0 * HH * 128];
    vf += gz[1 * HH * 128];
    vg += gz[2 * HH * 128];
    vo += gz[3 * HH * 128];
  }
  float ig = sigmoidf(vi), fg = sigmoidf(vf), gg = tanh_fast(vg), og = sigmoidf(vo);
  float cn = fg * cT[ch * 128 + b] + ig * gg;
  cT[ch * 128 + b] = cn;
  float hr = og * tanh_fast(cn);
  __shared__ float s1[2][128];
  s1[sub][b] = hr;
  __syncthreads();
  for (int off = 64; off > 0; off >>= 1) {
    if (b < off) s1[sub][b] += s1[sub][b + off];
    __syncthreads();
  }
  float mean = s1[sub][0] * (1.f / 128);
  __syncthreads();
  float dv = hr - mean;
  s1[sub][b] = dv * dv;
  __syncthreads();
  for (int off = 64; off > 0; off >>= 1) {
    if (b < off) s1[sub][b] += s1[sub][b + off];
    __syncthreads();
  }
  float var = s1[sub][0] * (1.f / 128);
  float res = dv * (1.f / sqrtf(var + EPSV)) * g1[ch] + be1[ch];
  hbf[(long)b * HH + ch] = f2b(res);
  xnext[(long)b * XW + EE + DD + ch] = f2b(res);
}

extern "C" void kernel_launch(void* const* d_in, const int* in_sizes, int n_in,
                              void* d_out, int out_size, void* d_ws, size_t ws_size,
                              hipStream_t stream) {
  const int* captions  = (const int*)d_in[0];
  const float* features = (const float*)d_in[1];
  const float* emb   = (const float*)d_in[2];
  const float* Wa    = (const float*)d_in[3];
  const float* ba    = (const float*)d_in[4];
  const float* Ua    = (const float*)d_in[5];
  const float* bu    = (const float*)d_in[6];
  const float* va    = (const float*)d_in[7];
  const float* bv    = (const float*)d_in[8];
  const float* W_ih  = (const float*)d_in[9];
  const float* b_ih  = (const float*)d_in[10];
  const float* W_hh  = (const float*)d_in[11];
  const float* b_hh  = (const float*)d_in[12];
  const float* g1    = (const float*)d_in[13];
  const float* be1   = (const float*)d_in[14];
  const float* fc_w  = (const float*)d_in[15];
  const float* fc_b  = (const float*)d_in[16];
  const float* g2    = (const float*)d_in[17];
  const float* be2   = (const float*)d_in[18];
  const float* fc2_w = (const float*)d_in[19];
  const float* fc2_b = (const float*)d_in[20];
  const float* ih_w  = (const float*)d_in[21];
  const float* ih_b  = (const float*)d_in[22];
  const float* ic_w  = (const float*)d_in[23];
  const float* ic_b  = (const float*)d_in[24];

  float* out = (float*)d_out;                 // [B,T,V]
  float* att_out = out + (long)BQ * TT * VV;  // [B,T,R]

  char* p = (char*)d_ws;
  auto alloc = [&](size_t bytes) { char* r = p; p += (bytes + 255) & ~255ULL; return r; };
  bf16* featbf = (bf16*)alloc((size_t)BQ * RR * DD * 2);
  bf16* meanbf = (bf16*)alloc((size_t)BQ * DD * 2);
  bf16* Wcat   = (bf16*)alloc((size_t)4 * HH * XW * 2);
  bf16* Wabf   = (bf16*)alloc((size_t)HH * DD * 2);
  bf16* UaTbf  = (bf16*)alloc((size_t)HH * HH * 2);
  bf16* fcwbf  = (bf16*)alloc((size_t)256 * HH * 2);
  bf16* fc2wbf = (bf16*)alloc((size_t)VV * 256 * 2);
  bf16* ihwbf  = (bf16*)alloc((size_t)HH * DD * 2);
  bf16* icwbf  = (bf16*)alloc((size_t)HH * DD * 2);
  bf16* att1bf = (bf16*)alloc((size_t)BQ * RR * HH * 2);
  bf16* xcat_all = (bf16*)alloc((size_t)(TT + 1) * BQ * XW * 2);
  bf16* hbf    = (bf16*)alloc((size_t)BQ * HH * 2);
  bf16* out2bf = (bf16*)alloc((size_t)BQ * 256 * 2);
  float* biasc = (float*)alloc((size_t)4 * HH * 4);
  float* cT    = (float*)alloc((size_t)BQ * HH * 4);
  float* gatesT = (float*)alloc((size_t)4 * BQ * 4 * HH * 4);  // 4 split-K partials, [ch][b]

  // ---- prologue ----
  f2b_kernel<<<(BQ * RR * DD / 4 + 255) / 256, 256, 0, stream>>>(features, featbf, BQ * RR * DD / 4);
  f2b_kernel<<<(HH * DD / 4 + 255) / 256, 256, 0, stream>>>(Wa, Wabf, HH * DD / 4);
  transpose_ua<<<dim3(8, 8), 256, 0, stream>>>(Ua, UaTbf);
  f2b_kernel<<<(256 * HH / 4 + 255) / 256, 256, 0, stream>>>(fc_w, fcwbf, 256 * HH / 4);
  f2b_kernel<<<(VV * 256 / 4 + 255) / 256, 256, 0, stream>>>(fc2_w, fc2wbf, VV * 256 / 4);
  f2b_kernel<<<(HH * DD / 4 + 255) / 256, 256, 0, stream>>>(ih_w, ihwbf, HH * DD / 4);
  f2b_kernel<<<(HH * DD / 4 + 255) / 256, 256, 0, stream>>>(ic_w, icwbf, HH * DD / 4);
  wcat_kernel<<<dim3(XW / 4 / 256, 4 * HH), 256, 0, stream>>>(W_ih, W_hh, Wcat);
  biasc_kernel<<<(4 * HH + 255) / 256, 256, 0, stream>>>(b_ih, b_hh, biasc);
  mean_kernel<<<(BQ * DD + 255) / 256, 256, 0, stream>>>(featbf, meanbf);
  embed_all_kernel<<<(BQ * TT * EE / 4) / 256, 256, 0, stream>>>(captions, emb, xcat_all);

  // h0 -> hbf + xcat_0 h-slice; c0 -> cT (fp32, transposed)
  gemm_mfma<<<dim3(HH / 64, 1), 256, 0, stream>>>(
      meanbf, ihwbf, ih_b, nullptr, hbf, xcat_all + EE + DD, HH, XW, HH, DD, 0, 0);
  gemm_mfma<<<dim3(HH / 64, 1), 256, 0, stream>>>(
      meanbf, icwbf, ic_b, cT, nullptr, nullptr, 128, 0, HH, DD, 0, 1);
  // att1 = features @ Wa^T + ba  (bf16 out)
  gemm_mfma<<<dim3(HH / 64, BQ * RR / 128), 256, 0, stream>>>(
      featbf, Wabf, ba, nullptr, att1bf, nullptr, HH, 0, HH, DD, 0, 0);

  // ---- timestep loop: 3 kernels/step ----
  for (int t = 0; t < TT; ++t) {
    bf16* xc = xcat_all + (size_t)t * BQ * XW;
    bf16* xn = xcat_all + (size_t)(t + 1) * BQ * XW;
    // attn(t) || fc1+bn2 on h(t-1)
    step_attn_fc<<<160, 512, 0, stream>>>(
        att1bf, hbf, UaTbf, bu, va, bv, featbf, xc, att_out, t, 1,
        fcwbf, fc_b, g2, be2, out2bf, t > 0 ? 1 : 0);
    // gates(t) || fc2(t-1)
    step_gemms<<<285, 256, 0, stream>>>(
        xc, Wcat, biasc, gatesT, out2bf, fc2wbf, fc2_b,
        out + (long)(t > 0 ? t - 1 : 0) * VV, 1, t > 0 ? 1 : 0);
    // lstm + bn1 -> h(t)
    lstm_bn2<<<HH / 2, 256, 0, stream>>>(gatesT, cT, hbf, xn, g1, be1);
  }
  // tail: fc1+bn2 and fc2 for t = TT-1
  step_attn_fc<<<160, 512, 0, stream>>>(
      att1bf, hbf, UaTbf, bu, va, bv, featbf, xcat_all, att_out, 0, 0,
      fcwbf, fc_b, g2, be2, out2bf, 1);
  step_gemms<<<285, 256, 0, stream>>>(
      xcat_all, Wcat, biasc, gatesT, out2bf, fc2wbf, fc2_b,
      out + (long)(TT - 1) * VV, 0, 1);
}